// Round 1
// baseline (30.915 us; speedup 1.0000x reference)
//
#include <hip/hip_runtime.h>

#define HH 14
#define WW 14
#define P 196          // HH*WW
#define SENT 196
#define CTOT 2048
#define NCHUNK 16
#define CCHUNK 128     // CTOT/NCHUNK
#define Q4 49          // P/4 float4 per channel row

// ---------------- kernel 1: partial channel sums ----------------
// grid = 64*NCHUNK blocks, 256 threads. Block (b,k) sums channels
// [k*CCHUNK, (k+1)*CCHUNK) into partials[b*NCHUNK+k][196].
__global__ __launch_bounds__(256) void chansum_kernel(const float* __restrict__ fms,
                                                      float* __restrict__ partials) {
    const int blk = blockIdx.x;
    const int b = blk >> 4;       // /NCHUNK
    const int k = blk & 15;       // %NCHUNK
    const float4* __restrict__ base =
        (const float4*)(fms + ((size_t)b * CTOT + (size_t)k * CCHUNK) * P);

    __shared__ float lds[5 * P];
    const int t = threadIdx.x;

    if (t < 5 * Q4) {             // 245 active lanes
        const int q = t % Q4;     // float4 column within row
        const int r = t / Q4;     // row-group 0..4
        float4 acc = {0.f, 0.f, 0.f, 0.f};
        #pragma unroll 4
        for (int c = r; c < CCHUNK; c += 5) {
            float4 v = base[c * Q4 + q];
            acc.x += v.x; acc.y += v.y; acc.z += v.z; acc.w += v.w;
        }
        const int o = r * P + q * 4;
        lds[o + 0] = acc.x; lds[o + 1] = acc.y;
        lds[o + 2] = acc.z; lds[o + 3] = acc.w;
    }
    __syncthreads();
    if (t < P) {
        float s = lds[t] + lds[P + t] + lds[2 * P + t] + lds[3 * P + t] + lds[4 * P + t];
        partials[(size_t)blk * P + t] = s;
    }
}

// ---------------- kernel 2: threshold + CC + bbox ----------------
// grid = 64 blocks (one per batch), 256 threads.
__global__ __launch_bounds__(256) void bbox_kernel(const float* __restrict__ partials,
                                                   int* __restrict__ out) {
    const int b = blockIdx.x;
    const int t = threadIdx.x;

    __shared__ float att[P];
    __shared__ int   lab[P];
    __shared__ int   cnt[P];
    __shared__ float redf[256];
    __shared__ int   redi[256];
    __shared__ int   wr[4][4];
    __shared__ int   chg;

    // sum partials -> attention (sum; /2048 irrelevant to a relative threshold,
    // margin is ~54 sigma so rounding cannot flip the mask)
    float a = 0.f;
    if (t < P) {
        #pragma unroll
        for (int k = 0; k < NCHUNK; ++k)
            a += partials[((size_t)b * NCHUNK + k) * P + t];
        att[t] = a;
    }

    // block max reduce
    redf[t] = (t < P) ? a : -1e30f;
    __syncthreads();
    for (int s = 128; s > 0; s >>= 1) {
        if (t < s) redf[t] = fmaxf(redf[t], redf[t + s]);
        __syncthreads();
    }
    const float maxv = redf[0];

    const bool maskp = (t < P) && (att[t] > maxv * 0.3f);
    if (t < P) lab[t] = maskp ? t : SENT;
    if (t == 0) chg = 0;
    __syncthreads();

    // Jacobi min-label propagation (8-connectivity) until convergence.
    // Same fixed point as the reference's 196 fixed iterations.
    const int row = t / WW;
    const int col = t % WW;
    for (;;) {
        int m2 = SENT;
        if (maskp) {
            m2 = lab[t];
            #pragma unroll
            for (int dr = -1; dr <= 1; ++dr) {
                #pragma unroll
                for (int dc = -1; dc <= 1; ++dc) {
                    int rr = row + dr, cc = col + dc;
                    if (rr >= 0 && rr < HH && cc >= 0 && cc < WW)
                        m2 = min(m2, lab[rr * WW + cc]);
                }
            }
        }
        __syncthreads();                       // A: all reads done
        if (maskp && m2 < lab[t]) { lab[t] = m2; chg = 1; }
        __syncthreads();                       // B: all writes done
        const int c = chg;
        __syncthreads();                       // C: all have read chg
        if (t == 0) chg = 0;                   // reset happens-before next A
        if (!c) break;
    }

    // per-label counts
    if (t < P) cnt[t] = 0;
    __syncthreads();
    if (t < P && lab[t] != SENT) atomicAdd(&cnt[lab[t]], 1);
    __syncthreads();

    // argmax(count), ties -> smallest label: key = cnt*256 + (255 - label)
    redi[t] = (t < P) ? (cnt[t] * 256 + (255 - t)) : 0;
    __syncthreads();
    for (int s = 128; s > 0; s >>= 1) {
        if (t < s) redi[t] = max(redi[t], redi[t + s]);
        __syncthreads();
    }
    const int bkey = redi[0];
    const int best = 255 - (bkey & 255);
    const int bcnt = bkey >> 8;

    // bbox of selected component: wave shfl reduce then cross-wave combine
    int mnr = HH, mxr = -1, mnc = WW, mxc = -1;
    if (t < P && bcnt > 0 && lab[t] == best) {
        mnr = row; mxr = row; mnc = col; mxc = col;
    }
    #pragma unroll
    for (int off = 32; off > 0; off >>= 1) {
        mnr = min(mnr, __shfl_down(mnr, off));
        mxr = max(mxr, __shfl_down(mxr, off));
        mnc = min(mnc, __shfl_down(mnc, off));
        mxc = max(mxc, __shfl_down(mxc, off));
    }
    const int wid = t >> 6;
    if ((t & 63) == 0) { wr[0][wid] = mnr; wr[1][wid] = mxr; wr[2][wid] = mnc; wr[3][wid] = mxc; }
    __syncthreads();

    if (t == 0) {
        for (int w2 = 1; w2 < 4; ++w2) {
            mnr = min(mnr, wr[0][w2]); mxr = max(mxr, wr[1][w2]);
            mnc = min(mnc, wr[2][w2]); mxc = max(mxc, wr[3][w2]);
        }
        if (bcnt == 0) { mnr = 0; mxr = HH - 1; mnc = 0; mxc = WW - 1; }  // empty fallback
        const int x0 = max(mnr * 32 - 1, 0);
        const int y0 = max(mnc * 32 - 1, 0);
        const int x1 = (mxr + 1) * 32 - 1;
        const int y1 = (mxc + 1) * 32 - 1;
        out[b * 4 + 0] = x0;
        out[b * 4 + 1] = y0;
        out[b * 4 + 2] = x1;
        out[b * 4 + 3] = y1;
    }
}

extern "C" void kernel_launch(void* const* d_in, const int* in_sizes, int n_in,
                              void* d_out, int out_size, void* d_ws, size_t ws_size,
                              hipStream_t stream) {
    const float* fms = (const float*)d_in[0];
    int* out = (int*)d_out;
    float* partials = (float*)d_ws;   // 64 * NCHUNK * 196 floats = 802,816 B

    chansum_kernel<<<dim3(64 * NCHUNK), dim3(256), 0, stream>>>(fms, partials);
    bbox_kernel<<<dim3(64), dim3(256), 0, stream>>>(partials, out);
}